// Round 1
// baseline (1219.382 us; speedup 1.0000x reference)
//
#include <hip/hip_runtime.h>
#include <math.h>

#define N_NODES 100000
#define N_EDGES 1600000
#define ETOT    (N_EDGES + N_NODES)
#define NHEAD   4
#define ED      8

// ---------------- CSR build (graph is shared by both layers) ----------------

__global__ void count_kernel(const int* __restrict__ ei, int* __restrict__ counts) {
    int e = blockIdx.x * 256 + threadIdx.x;
    if (e >= ETOT) return;
    int d = (e < N_EDGES) ? ei[N_EDGES + e] : (e - N_EDGES);
    atomicAdd(&counts[d], 1);
}

#define SCAN_CHUNK 1024
#define SCAN_NB    ((N_NODES + SCAN_CHUNK - 1) / SCAN_CHUNK)   // 98

__global__ void scan1_kernel(const int* __restrict__ counts, int* __restrict__ rowptr,
                             int* __restrict__ bsum) {
    __shared__ int tmp[SCAN_CHUNK];
    int t = threadIdx.x;
    int i = blockIdx.x * SCAN_CHUNK + t;
    int v = (i < N_NODES) ? counts[i] : 0;
    tmp[t] = v;
    __syncthreads();
    for (int off = 1; off < SCAN_CHUNK; off <<= 1) {
        int x = (t >= off) ? tmp[t - off] : 0;
        __syncthreads();
        tmp[t] += x;
        __syncthreads();
    }
    if (i < N_NODES) rowptr[i] = tmp[t] - v;     // exclusive, block-local
    if (t == SCAN_CHUNK - 1) bsum[blockIdx.x] = tmp[t];
}

__global__ void scan2_kernel(int* __restrict__ bsum) {
    if (threadIdx.x == 0 && blockIdx.x == 0) {
        int run = 0;
        for (int b = 0; b < SCAN_NB; ++b) { int t = bsum[b]; bsum[b] = run; run += t; }
    }
}

__global__ void scan3_kernel(int* __restrict__ rowptr, const int* __restrict__ bsum,
                             int* __restrict__ cursor) {
    int i = blockIdx.x * SCAN_CHUNK + threadIdx.x;
    if (i < N_NODES) {
        int v = rowptr[i] + bsum[blockIdx.x];
        rowptr[i] = v;
        cursor[i] = v;
    }
    if (i == 0) rowptr[N_NODES] = ETOT;
}

__global__ void fill_kernel(const int* __restrict__ ei, int* __restrict__ cursor,
                            int* __restrict__ esrc, int* __restrict__ eid) {
    int e = blockIdx.x * 256 + threadIdx.x;
    if (e >= ETOT) return;
    int s, d;
    if (e < N_EDGES) { s = ei[e]; d = ei[N_EDGES + e]; }
    else             { s = e - N_EDGES; d = s; }
    int p = atomicAdd(&cursor[d], 1);
    esrc[p] = s;
    eid[p]  = e;
}

// ---------------- per-layer: fold We/a_edge into M[8][4] ----------------

__global__ void make_M(const float* __restrict__ We, const float* __restrict__ a_edge,
                       float* __restrict__ M, int C) {
    int t = threadIdx.x;
    if (t >= ED * NHEAD) return;
    int d = t >> 2, h = t & 3;
    float s = 0.f;
    for (int c = 0; c < C; ++c) s += We[d * (NHEAD * C) + h * C + c] * a_edge[h * C + c];
    M[d * NHEAD + h] = s;
}

// ---------------- h = x @ W, plus per-node attention scalars ----------------
// block = CH threads, one node per block.

template <int FIN, int C>
__global__ void feat_kernel(const float* __restrict__ x, const float* __restrict__ W,
                            const float* __restrict__ a_src, const float* __restrict__ a_dst,
                            float* __restrict__ h, float* __restrict__ as_n,
                            float* __restrict__ ad_n) {
    constexpr int CH = NHEAD * C;
    int n = blockIdx.x;
    int t = threadIdx.x;            // 0..CH-1
    __shared__ float xs[FIN];
    if (t < FIN) xs[t] = x[(size_t)n * FIN + t];
    __syncthreads();
    float acc = 0.f;
#pragma unroll
    for (int d = 0; d < FIN; ++d) acc += xs[d] * W[d * CH + t];
    h[(size_t)n * CH + t] = acc;
    int head = t / C;
    int cl   = t % C;
    float sa = acc * a_src[head * C + cl];
    float sd = acc * a_dst[head * C + cl];
#pragma unroll
    for (int off = C / 2; off > 0; off >>= 1) {
        sa += __shfl_xor(sa, off);
        sd += __shfl_xor(sd, off);
    }
    if (cl == 0) {
        as_n[n * NHEAD + head] = sa;
        ad_n[n * NHEAD + head] = sd;
    }
}

// ---------------- flash-style GAT aggregation: one wave per dst node ----------------
// Online softmax over incoming edges; accumulator [H,C] in registers.

template <int C>
__global__ __launch_bounds__(256) void gat_aggregate(
    const int* __restrict__ rowptr, const int* __restrict__ esrc,
    const int* __restrict__ eid, const float* __restrict__ h,
    const float* __restrict__ as_n, const float* __restrict__ ad_n,
    const float* __restrict__ edge_attr, const float* __restrict__ M,
    const float* __restrict__ bias, float* __restrict__ out) {
    constexpr int CH  = NHEAD * C;
    constexpr int FPL = CH / 64;    // floats per lane: 2 (C=32) or 1 (C=16)
    int wave = threadIdx.x >> 6;
    int lane = threadIdx.x & 63;
    int n = blockIdx.x * 4 + wave;
    if (n >= N_NODES) return;
    int head = lane >> 4;           // 16 lanes per head
    int c0   = lane * FPL;          // global column start for this lane

    float ad = ad_n[n * NHEAD + head];
    float m = -3.0e38f, s = 0.f;
    float acc[FPL];
#pragma unroll
    for (int k = 0; k < FPL; ++k) acc[k] = 0.f;

    int p0 = rowptr[n], p1 = rowptr[n + 1];
    for (int p = p0; p < p1; ++p) {
        int sp = esrc[p];
        int e  = eid[p];
        float a = as_n[sp * NHEAD + head] + ad;
        if (e < N_EDGES) {
            const float* ear = edge_attr + (size_t)e * ED;
            float ae = 0.f;
#pragma unroll
            for (int d = 0; d < ED; ++d) ae += ear[d] * M[d * NHEAD + head];
            a += ae;
        }
        a = (a > 0.f) ? a : 0.2f * a;             // leaky_relu(0.2)
        float mn = fmaxf(m, a);
        float sc = __expf(m - mn);
        float pw = __expf(a - mn);
        s = s * sc + pw;
        const float* hr = h + (size_t)sp * CH + c0;
        if constexpr (FPL == 2) {
            float2 hv = *reinterpret_cast<const float2*>(hr);
            acc[0] = acc[0] * sc + pw * hv.x;
            acc[1] = acc[1] * sc + pw * hv.y;
        } else {
            acc[0] = acc[0] * sc + pw * hr[0];
        }
        m = mn;
    }

    float inv = 1.f / (s + 1e-16f);
    float v[FPL];
#pragma unroll
    for (int k = 0; k < FPL; ++k) v[k] = acc[k] * inv;
    // head mean: lanes {l, l^16, l^32, l^48} hold the same column of different heads
#pragma unroll
    for (int k = 0; k < FPL; ++k) {
        v[k] += __shfl_xor(v[k], 16);
        v[k] += __shfl_xor(v[k], 32);
    }
    if (lane < 16) {
#pragma unroll
        for (int k = 0; k < FPL; ++k) {
            int c = lane * FPL + k;             // column within C
            float o = 0.25f * v[k] + bias[c];
            o = (o > 0.f) ? o : expm1f(o);      // elu
            out[(size_t)n * C + c] = o;
        }
    }
}

// ---------------- launch ----------------

static inline size_t align_up(size_t x, size_t a) { return (x + a - 1) & ~(a - 1); }

extern "C" void kernel_launch(void* const* d_in, const int* in_sizes, int n_in,
                              void* d_out, int out_size, void* d_ws, size_t ws_size,
                              hipStream_t stream) {
    const float* x        = (const float*)d_in[0];
    const int*   ei       = (const int*)d_in[1];    // [2, E]
    const float* ea       = (const float*)d_in[2];  // [E, 8]
    const float* W1       = (const float*)d_in[3];
    const float* We1      = (const float*)d_in[4];
    const float* a_src1   = (const float*)d_in[5];
    const float* a_dst1   = (const float*)d_in[6];
    const float* a_edge1  = (const float*)d_in[7];
    const float* b1       = (const float*)d_in[8];
    const float* W2       = (const float*)d_in[9];
    const float* We2      = (const float*)d_in[10];
    const float* a_src2   = (const float*)d_in[11];
    const float* a_dst2   = (const float*)d_in[12];
    const float* a_edge2  = (const float*)d_in[13];
    const float* b2       = (const float*)d_in[14];
    float* out = (float*)d_out;

    // workspace carve-up
    char* p = (char*)d_ws;
    auto take = [&](size_t bytes) { char* r = p; p += align_up(bytes, 256); return r; };
    int*   counts = (int*)take(sizeof(int) * N_NODES);
    int*   rowptr = (int*)take(sizeof(int) * (N_NODES + 1));
    int*   cursor = (int*)take(sizeof(int) * N_NODES);
    int*   bsum   = (int*)take(sizeof(int) * 128);
    int*   esrc   = (int*)take(sizeof(int) * ETOT);
    int*   eid    = (int*)take(sizeof(int) * ETOT);
    float* hbuf   = (float*)take(sizeof(float) * (size_t)N_NODES * 128);
    float* as_n   = (float*)take(sizeof(float) * N_NODES * NHEAD);
    float* ad_n   = (float*)take(sizeof(float) * N_NODES * NHEAD);
    float* x2     = (float*)take(sizeof(float) * (size_t)N_NODES * 32);
    float* M      = (float*)take(sizeof(float) * ED * NHEAD);

    // ---- CSR build ----
    hipMemsetAsync(counts, 0, sizeof(int) * N_NODES, stream);
    int egrid = (ETOT + 255) / 256;
    count_kernel<<<egrid, 256, 0, stream>>>(ei, counts);
    scan1_kernel<<<SCAN_NB, SCAN_CHUNK, 0, stream>>>(counts, rowptr, bsum);
    scan2_kernel<<<1, 1, 0, stream>>>(bsum);
    scan3_kernel<<<SCAN_NB, SCAN_CHUNK, 0, stream>>>(rowptr, bsum, cursor);
    fill_kernel<<<egrid, 256, 0, stream>>>(ei, cursor, esrc, eid);

    int ngrid4 = (N_NODES + 3) / 4;

    // ---- layer 1: Fin=64, C=32 ----
    make_M<<<1, 32, 0, stream>>>(We1, a_edge1, M, 32);
    feat_kernel<64, 32><<<N_NODES, 128, 0, stream>>>(x, W1, a_src1, a_dst1, hbuf, as_n, ad_n);
    gat_aggregate<32><<<ngrid4, 256, 0, stream>>>(rowptr, esrc, eid, hbuf, as_n, ad_n,
                                                  ea, M, b1, x2);

    // ---- layer 2: Fin=32, C=16 ----
    make_M<<<1, 32, 0, stream>>>(We2, a_edge2, M, 16);
    feat_kernel<32, 16><<<N_NODES, 64, 0, stream>>>(x2, W2, a_src2, a_dst2, hbuf, as_n, ad_n);
    gat_aggregate<16><<<ngrid4, 256, 0, stream>>>(rowptr, esrc, eid, hbuf, as_n, ad_n,
                                                  ea, M, b2, out);
}